// Round 6
// baseline (283.535 us; speedup 1.0000x reference)
//
#include <hip/hip_runtime.h>
#include <hip/hip_bf16.h>

// Problem constants (B=8, S=8192, K=1024, N=1024, G=128)
#define M_DIM 65536
#define K_DIM 1024
#define N_DIM 1024
#define NGRP  8

// 256x256 4-phase GEMM geometry (merged-phase m201 variant)
#define G_BM 256
#define G_BN 256
#define NKT64 (K_DIM / 64)      // 16 K-tiles of 64
#define NIT   (K_DIM / 128)     // 8 iterations (2 K-tiles each)

// fallback geometry (round-1 fused kernel)
#define FB_BM 128
#define FB_BN 128
#define FB_BK 32
#define FB_NKT (K_DIM / FB_BK)

typedef float f32x4 __attribute__((ext_vector_type(4)));
typedef __bf16 bf16x8 __attribute__((ext_vector_type(8)));

// ---------------- prep: dequant W -> bf16 [N][K], bias -> f32 ----------------
__global__ void prep_kernel(const int* __restrict__ w_q,
                            const float* __restrict__ w_scale,
                            const int* __restrict__ w_zp,
                            const int* __restrict__ bias_q,
                            const float* __restrict__ bias_scale,
                            __hip_bfloat16* __restrict__ Wb,
                            float* __restrict__ bias_f) {
    const int n = blockIdx.x;       // 0..1023
    const int t = threadIdx.x;      // 0..255
    const int k0 = t * 4;
    const int g = k0 >> 7;          // group of 128
    const float s  = w_scale[n * NGRP + g];
    const float zp = (float)w_zp[n * NGRP + g];
    const int4 wq = *reinterpret_cast<const int4*>(w_q + (size_t)n * K_DIM + k0);
    union { ushort4 u; __hip_bfloat16 h[4]; } pk;
    pk.h[0] = __float2bfloat16(((float)wq.x - zp) * s);
    pk.h[1] = __float2bfloat16(((float)wq.y - zp) * s);
    pk.h[2] = __float2bfloat16(((float)wq.z - zp) * s);
    pk.h[3] = __float2bfloat16(((float)wq.w - zp) * s);
    *reinterpret_cast<ushort4*>(Wb + (size_t)n * K_DIM + k0) = pk.u;
    if (t == 0) bias_f[n] = ((float)bias_q[n] - 128.0f) * bias_scale[n];
}

// ---------------- prep: fake-quant x -> bf16 [M][K] ----------------
__global__ __launch_bounds__(256) void prep_x_kernel(
    const float* __restrict__ x,
    const float* __restrict__ in_scale_p, const int* __restrict__ in_zp_p,
    __hip_bfloat16* __restrict__ Xq)
{
    const float s = in_scale_p[0];
    const float inv = 1.0f / s;
    const float zp = (float)in_zp_p[0];
    const size_t i = ((size_t)blockIdx.x * 256 + threadIdx.x) * 8;
    const float4 v0 = *reinterpret_cast<const float4*>(x + i);
    const float4 v1 = *reinterpret_cast<const float4*>(x + i + 4);
    float vv[8] = {v0.x, v0.y, v0.z, v0.w, v1.x, v1.y, v1.z, v1.w};
    union { uint4 u; __hip_bfloat16 h[8]; } pk;
#pragma unroll
    for (int e = 0; e < 8; ++e) {
        float q = rintf(vv[e] * inv) + zp;       // RNE matches jnp.round
        q = fminf(fmaxf(q, -128.0f), 127.0f);
        pk.h[e] = __float2bfloat16((q - zp) * s);
    }
    *reinterpret_cast<uint4*>(Xq + i) = pk.u;
}

// ---------------- 256x256 4-phase GEMM (merged phases, slot ring) ----------------
// LDS: 8 slots x 16 KiB. s0=A(2it,kk0) s1=B(2it,kk0) s2=A(2it,kk1) s3=B(2it,kk1)
//      s4=A(2it+1,kk0) s5=B(2it+1,kk0) s6=A(2it+1,kk1) s7=B(2it+1,kk1)
// Phase = {12 ds_read_b128 (A both m-halves + B) | 2 stages | vmcnt(W) |
//          barrier | lgkmcnt(0) | 32 MFMA | barrier}.
// Per-thread load ledger (2 loads/stage, 2 stages/phase = 4/phase):
//   prologue: 12 issued, vmcnt(8) retires s0,s1.
//   steady:   each phase issues 4 -> 12 outstanding; vmcnt(8) retires the
//             2 oldest slots = exactly the NEXT phase's read slots (staged
//             2 phases = ~1000 cyc earlier > HBM latency).
//   tail:     waits {8,4,0,0} retire s2s3 / s4s5 / s6s7 ahead of reads.
// WAR: slot restaged one phase after its last read; reads drained by that
// phase's lgkmcnt(0), which precedes the close barrier the stage waits on.
__global__ __launch_bounds__(512, 2) void gemm256_4ph_kernel(
    const __hip_bfloat16* __restrict__ Xq,
    const __hip_bfloat16* __restrict__ Wb,
    const float* __restrict__ bias_f,
    const float* __restrict__ out_scale_p, const int* __restrict__ out_zp_p,
    float* __restrict__ out)
{
    __shared__ __align__(16) __hip_bfloat16 LDS[8][8192];   // 128 KiB

    const int t = threadIdx.x;
    // bijective XCD swizzle: grid=1024, 8 XCDs, 128 blocks/XCD;
    // consecutive bids within an XCD share the A panel (mt).
    const int bid = (blockIdx.x & 7) * 128 + (blockIdx.x >> 3);
    const int nt = bid & 3;
    const int mt = bid >> 2;
    const int m0 = mt * G_BM;
    const int n0 = nt * G_BN;

    const int wid = t >> 6;
    const int lane = t & 63;
    const int wr = wid >> 2, wc = wid & 3;     // 2x4 waves, each owns 128x64 output
    const int lrow = lane & 15;
    const int kslot = lane >> 4;               // k-chunk (8 bf16) within 32-k slot
    const int koff = ((kslot ^ ((lrow >> 1) & 3)) << 4);
    const int widoff = wid * 1024;

    char* ldsb = (char*)&LDS[0][0];
    const __hip_bfloat16* Abase = Xq + (size_t)m0 * K_DIM;
    const __hip_bfloat16* Bbase = Wb + (size_t)n0 * K_DIM;

    // stage one half-tile slot (16 KiB = 256 rows x 32 k) via global_load_lds,
    // pre-swizzled source (both-sides rule; verified 0 conflicts r2/r3/r5)
    auto stage = [&](int slot, const __hip_bfloat16* panel, int ktile, int kk) {
        const int k0 = ktile * 64 + kk * 32;
#pragma unroll
        for (int j = 0; j < 2; ++j) {
            const int c = j * 512 + t;                 // 16B chunk id 0..1023
            const int r = c >> 2;                      // row 0..255
            const int sl = (c & 3) ^ ((r >> 1) & 3);   // logical k-slot at this phys slot
            const __hip_bfloat16* src = panel + (size_t)r * K_DIM + k0 + sl * 8;
            __builtin_amdgcn_global_load_lds(
                (const __attribute__((address_space(1))) void*)src,
                (__attribute__((address_space(3))) void*)(ldsb + slot * 16384 + j * 8192 + widoff),
                16, 0, 0);
        }
    };

    bf16x8 af[8], bfr[4];
    auto rdA8 = [&](int slot) {          // A fragment, both m-halves (8 x b128)
        const char* base = ldsb + slot * 16384;
#pragma unroll
        for (int i = 0; i < 8; ++i) {
            const int row = wr * 128 + i * 16 + lrow;
            af[i] = *reinterpret_cast<const bf16x8*>(base + row * 64 + koff);
        }
    };
    auto rdB = [&](int slot) {           // B fragment (4 x b128)
        const char* base = ldsb + slot * 16384;
#pragma unroll
        for (int i = 0; i < 4; ++i) {
            const int row = wc * 64 + i * 16 + lrow;
            bfr[i] = *reinterpret_cast<const bf16x8*>(base + row * 64 + koff);
        }
    };

    f32x4 acc[8][4];
#pragma unroll
    for (int mi = 0; mi < 8; ++mi)
#pragma unroll
        for (int ni = 0; ni < 4; ++ni)
            acc[mi][ni] = (f32x4){0.f, 0.f, 0.f, 0.f};

// one merged phase: 12 ds_reads | 2 stages | vmcnt(WN) | barrier | lgkm | 32 MFMA | barrier
#define PH4(SA, SB, STG1, STG2, WN)                                           \
    do {                                                                      \
        rdB(SB); rdA8(SA);                                                    \
        STG1;                                                                 \
        STG2;                                                                 \
        asm volatile("s_waitcnt vmcnt(" #WN ")" ::: "memory");                \
        __builtin_amdgcn_s_barrier();                                         \
        asm volatile("s_waitcnt lgkmcnt(0)" ::: "memory");                    \
        __builtin_amdgcn_sched_barrier(0);                                    \
        __builtin_amdgcn_s_setprio(1);                                        \
        _Pragma("unroll")                                                     \
        for (int mi = 0; mi < 8; ++mi)                                        \
            _Pragma("unroll")                                                 \
            for (int ni = 0; ni < 4; ++ni)                                    \
                acc[mi][ni] = __builtin_amdgcn_mfma_f32_16x16x32_bf16(        \
                    af[mi], bfr[ni], acc[mi][ni], 0, 0, 0);                   \
        __builtin_amdgcn_s_setprio(0);                                        \
        __builtin_amdgcn_s_barrier();                                         \
        __builtin_amdgcn_sched_barrier(0);                                    \
    } while (0)

    // prologue: stage slots 0..5, then retire s0,s1 before ph0's reads
    stage(0, Abase, 0, 0);
    stage(1, Bbase, 0, 0);
    stage(2, Abase, 0, 1);
    stage(3, Bbase, 0, 1);
    stage(4, Abase, 1, 0);
    stage(5, Bbase, 1, 0);
    asm volatile("s_waitcnt vmcnt(8)" ::: "memory");
    __builtin_amdgcn_s_barrier();
    __builtin_amdgcn_sched_barrier(0);

#pragma unroll 1
    for (int it = 0; it < NIT - 1; ++it) {
        const int tA = 2 * it + 1;       // <= 13
        const int tB = 2 * it + 2;       // <= 14
        const int tC = 2 * it + 3;       // <= 15

        PH4(0, 1, stage(6, Abase, tA, 1), stage(7, Bbase, tA, 1), 8);
        PH4(2, 3, stage(0, Abase, tB, 0), stage(1, Bbase, tB, 0), 8);
        PH4(4, 5, stage(2, Abase, tB, 1), stage(3, Bbase, tB, 1), 8);
        PH4(6, 7, stage(4, Abase, tC, 0), stage(5, Bbase, tC, 0), 8);
    }

    // peeled last iteration (tA = 15; no tB/tC stages): draining waits
    {
        const int tA = 2 * (NIT - 1) + 1;    // 15
        PH4(0, 1, stage(6, Abase, tA, 1), stage(7, Bbase, tA, 1), 8);
        PH4(2, 3, (void)0, (void)0, 4);
        PH4(4, 5, (void)0, (void)0, 0);
        PH4(6, 7, (void)0, (void)0, 0);
    }

#undef PH4

    // ---- epilogue: bias + output fake-quant ----
    const float out_s = out_scale_p[0];
    const float out_inv = 1.0f / out_s;
    const float ozp = (float)out_zp_p[0];
    const int col = lane & 15;
    const int rgrp = lane >> 4;
#pragma unroll
    for (int ni = 0; ni < 4; ++ni) {
        const int n = n0 + wc * 64 + ni * 16 + col;
        const float bv = bias_f[n];
#pragma unroll
        for (int mi = 0; mi < 8; ++mi) {
#pragma unroll
            for (int j = 0; j < 4; ++j) {
                const int m = m0 + wr * 128 + mi * 16 + rgrp * 4 + j;
                float v = acc[mi][ni][j] + bv;
                float q = rintf(v * out_inv) + ozp;
                q = fminf(fmaxf(q, -128.0f), 127.0f);
                out[(size_t)m * N_DIM + n] = (q - ozp) * out_s;
            }
        }
    }
}

// ---------------- fallback (round-1): fused quant in A-staging, f32 x ----------------
__global__ __launch_bounds__(256) void gemm_fused_kernel(
    const float* __restrict__ x,
    const __hip_bfloat16* __restrict__ Wb,
    const float* __restrict__ bias_f,
    const float* __restrict__ in_scale_p, const int* __restrict__ in_zp_p,
    const float* __restrict__ out_scale_p, const int* __restrict__ out_zp_p,
    float* __restrict__ out)
{
    __shared__ __align__(16) __hip_bfloat16 As[2][FB_BM][FB_BK];
    __shared__ __align__(16) __hip_bfloat16 Bs[2][FB_BN][FB_BK];

    const int t = threadIdx.x;
    const int bid = blockIdx.x;
    const int nt = bid & 7;
    const int mt = bid >> 3;
    const int m0 = mt * FB_BM;
    const int n0 = nt * FB_BN;

    const int wid = t >> 6;
    const int lane = t & 63;
    const int wr = wid >> 1, wc = wid & 1;
    const int lrow = lane & 15;
    const int kslot = lane >> 4;

    const float in_s = in_scale_p[0];
    const float in_inv = 1.0f / in_s;
    const float izp = (float)in_zp_p[0];

    auto stageB = [&](int b, int kt) {
        const int k0 = kt * FB_BK;
#pragma unroll
        for (int j = 0; j < 2; ++j) {
            const int c = (wid * 2 + j) * 64 + lane;
            const int row = c >> 2;
            const int slot = c & 3;
            const __hip_bfloat16* src = Wb + (size_t)(n0 + row) * K_DIM + k0 + slot * 8;
            __builtin_amdgcn_global_load_lds(
                (const __attribute__((address_space(1))) void*)src,
                (__attribute__((address_space(3))) void*)((char*)&Bs[b][0][0] + (wid * 2 + j) * 1024),
                16, 0, 0);
        }
    };
    auto stageA = [&](int b, int kt) {
        const int k0 = kt * FB_BK;
#pragma unroll
        for (int i = 0; i < 4; ++i) {
            const int c = t + 256 * i;
            const int row = c >> 3;
            const int slot = c & 7;
            const float4 v = *reinterpret_cast<const float4*>(
                x + (size_t)(m0 + row) * K_DIM + k0 + slot * 4);
            float vv[4] = {v.x, v.y, v.z, v.w};
            union { ushort4 u; __hip_bfloat16 h[4]; } pk;
#pragma unroll
            for (int e = 0; e < 4; ++e) {
                float q = rintf(vv[e] * in_inv) + izp;
                q = fminf(fmaxf(q, -128.0f), 127.0f);
                pk.h[e] = __float2bfloat16((q - izp) * in_s);
            }
            *reinterpret_cast<ushort4*>(&As[b][row][slot * 4]) = pk.u;
        }
    };

    f32x4 acc[4][4];
#pragma unroll
    for (int mi = 0; mi < 4; ++mi)
#pragma unroll
        for (int ni = 0; ni < 4; ++ni)
            acc[mi][ni] = (f32x4){0.f, 0.f, 0.f, 0.f};

    stageB(0, 0);
    stageA(0, 0);
    __syncthreads();

    for (int kt = 0; kt < FB_NKT; ++kt) {
        const int buf = kt & 1;
        if (kt + 1 < FB_NKT) {
            stageB(buf ^ 1, kt + 1);
            stageA(buf ^ 1, kt + 1);
        }
        bf16x8 af[4], bfr[4];
#pragma unroll
        for (int mi = 0; mi < 4; ++mi)
            af[mi] = *reinterpret_cast<const bf16x8*>(&As[buf][wr * 64 + mi * 16 + lrow][kslot * 8]);
#pragma unroll
        for (int ni = 0; ni < 4; ++ni)
            bfr[ni] = *reinterpret_cast<const bf16x8*>(&Bs[buf][wc * 64 + ni * 16 + lrow][kslot * 8]);
#pragma unroll
        for (int mi = 0; mi < 4; ++mi)
#pragma unroll
            for (int ni = 0; ni < 4; ++ni)
                acc[mi][ni] = __builtin_amdgcn_mfma_f32_16x16x32_bf16(af[mi], bfr[ni], acc[mi][ni], 0, 0, 0);
        __syncthreads();
    }

    const float out_s = out_scale_p[0];
    const float out_inv = 1.0f / out_s;
    const float ozp = (float)out_zp_p[0];
    const int col = lane & 15;
    const int rgrp = lane >> 4;
#pragma unroll
    for (int ni = 0; ni < 4; ++ni) {
        const int n = n0 + wc * 64 + ni * 16 + col;
        const float bv = bias_f[n];
#pragma unroll
        for (int mi = 0; mi < 4; ++mi) {
#pragma unroll
            for (int j = 0; j < 4; ++j) {
                const int m = m0 + wr * 64 + mi * 16 + rgrp * 4 + j;
                float v = acc[mi][ni][j] + bv;
                float q = rintf(v * out_inv) + ozp;
                q = fminf(fmaxf(q, -128.0f), 127.0f);
                out[(size_t)m * N_DIM + n] = (q - ozp) * out_s;
            }
        }
    }
}

extern "C" void kernel_launch(void* const* d_in, const int* in_sizes, int n_in,
                              void* d_out, int out_size, void* d_ws, size_t ws_size,
                              hipStream_t stream) {
    const float* x          = (const float*)d_in[0];
    const int*   w_q        = (const int*)d_in[1];
    const float* w_scale    = (const float*)d_in[2];
    const int*   w_zp       = (const int*)d_in[3];
    const int*   bias_q     = (const int*)d_in[4];
    const float* bias_scale = (const float*)d_in[5];
    const float* in_scale   = (const float*)d_in[6];
    const int*   in_zp      = (const int*)d_in[7];
    const float* out_scale  = (const float*)d_in[8];
    const int*   out_zp     = (const int*)d_in[9];

    const size_t xq_bytes = (size_t)M_DIM * K_DIM * sizeof(__hip_bfloat16);  // 134 MB
    const size_t wb_bytes = (size_t)N_DIM * K_DIM * sizeof(__hip_bfloat16);  // 2 MB
    const size_t need = xq_bytes + wb_bytes + (size_t)N_DIM * sizeof(float);

    if (ws_size >= need) {
        __hip_bfloat16* Xq = (__hip_bfloat16*)d_ws;
        __hip_bfloat16* Wb = (__hip_bfloat16*)((char*)d_ws + xq_bytes);
        float* bias_f = (float*)((char*)d_ws + xq_bytes + wb_bytes);

        prep_kernel<<<N_DIM, 256, 0, stream>>>(w_q, w_scale, w_zp, bias_q, bias_scale, Wb, bias_f);
        prep_x_kernel<<<(M_DIM * (size_t)K_DIM) / (256 * 8), 256, 0, stream>>>(x, in_scale, in_zp, Xq);

        const int grid = (M_DIM / G_BM) * (N_DIM / G_BN);   // 256 * 4 = 1024
        gemm256_4ph_kernel<<<grid, 512, 0, stream>>>(Xq, Wb, bias_f, out_scale, out_zp, (float*)d_out);
    } else {
        __hip_bfloat16* Wb = (__hip_bfloat16*)d_ws;
        float* bias_f = (float*)((char*)d_ws + wb_bytes);

        prep_kernel<<<N_DIM, 256, 0, stream>>>(w_q, w_scale, w_zp, bias_q, bias_scale, Wb, bias_f);
        const int grid = (M_DIM / FB_BM) * (N_DIM / FB_BN);
        gemm_fused_kernel<<<grid, 256, 0, stream>>>(x, Wb, bias_f, in_scale, in_zp,
                                                    out_scale, out_zp, (float*)d_out);
    }
}

// Round 7
// 259.874 us; speedup vs baseline: 1.0910x; 1.0910x over previous
//
#include <hip/hip_runtime.h>
#include <hip/hip_bf16.h>

// Problem constants (B=8, S=8192, K=1024, N=1024, G=128)
#define M_DIM 65536
#define K_DIM 1024
#define N_DIM 1024
#define NGRP  8

// 256x256 8-phase GEMM geometry
#define G_BM 256
#define G_BN 256
#define NKT64 (K_DIM / 64)      // 16 K-tiles of 64
#define NIT   (K_DIM / 128)     // 8 iterations (2 K-tiles each)

// fallback geometry (round-1 fused kernel)
#define FB_BM 128
#define FB_BN 128
#define FB_BK 32
#define FB_NKT (K_DIM / FB_BK)

typedef float f32x4 __attribute__((ext_vector_type(4)));
typedef __bf16 bf16x8 __attribute__((ext_vector_type(8)));

// ---------------- prep: dequant W -> bf16 [N][K], bias -> f32 ----------------
__global__ void prep_kernel(const int* __restrict__ w_q,
                            const float* __restrict__ w_scale,
                            const int* __restrict__ w_zp,
                            const int* __restrict__ bias_q,
                            const float* __restrict__ bias_scale,
                            __hip_bfloat16* __restrict__ Wb,
                            float* __restrict__ bias_f) {
    const int n = blockIdx.x;       // 0..1023
    const int t = threadIdx.x;      // 0..255
    const int k0 = t * 4;
    const int g = k0 >> 7;          // group of 128
    const float s  = w_scale[n * NGRP + g];
    const float zp = (float)w_zp[n * NGRP + g];
    const int4 wq = *reinterpret_cast<const int4*>(w_q + (size_t)n * K_DIM + k0);
    union { ushort4 u; __hip_bfloat16 h[4]; } pk;
    pk.h[0] = __float2bfloat16(((float)wq.x - zp) * s);
    pk.h[1] = __float2bfloat16(((float)wq.y - zp) * s);
    pk.h[2] = __float2bfloat16(((float)wq.z - zp) * s);
    pk.h[3] = __float2bfloat16(((float)wq.w - zp) * s);
    *reinterpret_cast<ushort4*>(Wb + (size_t)n * K_DIM + k0) = pk.u;
    if (t == 0) bias_f[n] = ((float)bias_q[n] - 128.0f) * bias_scale[n];
}

// ---------------- prep: fake-quant x -> bf16 [M][K] ----------------
__global__ __launch_bounds__(256) void prep_x_kernel(
    const float* __restrict__ x,
    const float* __restrict__ in_scale_p, const int* __restrict__ in_zp_p,
    __hip_bfloat16* __restrict__ Xq)
{
    const float s = in_scale_p[0];
    const float inv = 1.0f / s;
    const float zp = (float)in_zp_p[0];
    const size_t i = ((size_t)blockIdx.x * 256 + threadIdx.x) * 8;
    const float4 v0 = *reinterpret_cast<const float4*>(x + i);
    const float4 v1 = *reinterpret_cast<const float4*>(x + i + 4);
    float vv[8] = {v0.x, v0.y, v0.z, v0.w, v1.x, v1.y, v1.z, v1.w};
    union { uint4 u; __hip_bfloat16 h[8]; } pk;
#pragma unroll
    for (int e = 0; e < 8; ++e) {
        float q = rintf(vv[e] * inv) + zp;       // RNE matches jnp.round
        q = fminf(fmaxf(q, -128.0f), 127.0f);
        pk.h[e] = __float2bfloat16((q - zp) * s);
    }
    *reinterpret_cast<uint4*>(Xq + i) = pk.u;
}

// ---------------- 256x256 8-phase GEMM, single barrier/phase ----------------
// LDS: 8 slots x 16 KiB. s0=A(2it,kk0) s1=B(2it,kk0) s2=A(2it,kk1) s3=B(2it,kk1)
//      s4=A(2it+1,kk0) s5=B(2it+1,kk0) s6=A(2it+1,kk1) s7=B(2it+1,kk1)
// Phase = { ds_reads (compiler fine-grained lgkm) | 1 stage issue |
//           setprio(1) 16 MFMA setprio(0) | [vmcnt at ph3/ph7] |
//           sched_barrier | s_barrier | sched_barrier }.
// RAW (DMA->ds_read): reads of s0..s3 verified by PREVIOUS iter's ph7
//   {vmcnt(4); barrier}; reads of s4..s7 by THIS iter's ph3 {vmcnt(4); barrier}.
//   Ledger: stages/phase = 1 (2 loads); at ph3 & ph7 outstanding = 12 loads,
//   the 8 oldest are the 4 slots needed next -> vmcnt(4).
// WAR (ds_read->DMA restage): every ds_read feeds an MFMA before the close
//   barrier (compiler lgkm waits), and a slot is restaged only in the phase
//   AFTER its last read's close barrier.
// Prologue: 6 stages (12 loads), vmcnt(4) retires s0..s3, barrier.
// Tail iter: stages only at ph0/ph1; ph3 wait = vmcnt(0) (8 outstanding,
//   retires s4..s7); ph4-7 no stage, no wait.
__global__ __launch_bounds__(512, 2) void gemm256_sb_kernel(
    const __hip_bfloat16* __restrict__ Xq,
    const __hip_bfloat16* __restrict__ Wb,
    const float* __restrict__ bias_f,
    const float* __restrict__ out_scale_p, const int* __restrict__ out_zp_p,
    float* __restrict__ out)
{
    __shared__ __align__(16) __hip_bfloat16 LDS[8][8192];   // 128 KiB

    const int t = threadIdx.x;
    // bijective XCD swizzle: grid=1024, 8 XCDs, 128 blocks/XCD
    const int bid = (blockIdx.x & 7) * 128 + (blockIdx.x >> 3);
    const int nt = bid & 3;
    const int mt = bid >> 2;
    const int m0 = mt * G_BM;
    const int n0 = nt * G_BN;

    const int wid = t >> 6;
    const int lane = t & 63;
    const int wr = wid >> 2, wc = wid & 3;     // 2x4 waves, each owns 128x64 output
    const int lrow = lane & 15;
    const int kslot = lane >> 4;               // k-chunk (8 bf16) within 32-k slot
    const int koff = ((kslot ^ ((lrow >> 1) & 3)) << 4);
    const int widoff = wid * 1024;

    char* ldsb = (char*)&LDS[0][0];
    const __hip_bfloat16* Abase = Xq + (size_t)m0 * K_DIM;
    const __hip_bfloat16* Bbase = Wb + (size_t)n0 * K_DIM;

    // stage one half-tile slot (16 KiB = 256 rows x 32 k) via global_load_lds,
    // pre-swizzled source (both-sides rule; 0 conflicts measured r2/r3/r5/r6)
    auto stage = [&](int slot, const __hip_bfloat16* panel, int ktile, int kk) {
        const int k0 = ktile * 64 + kk * 32;
#pragma unroll
        for (int j = 0; j < 2; ++j) {
            const int c = j * 512 + t;                 // 16B chunk id 0..1023
            const int r = c >> 2;                      // row 0..255
            const int sl = (c & 3) ^ ((r >> 1) & 3);   // logical k-slot at this phys slot
            const __hip_bfloat16* src = panel + (size_t)r * K_DIM + k0 + sl * 8;
            __builtin_amdgcn_global_load_lds(
                (const __attribute__((address_space(1))) void*)src,
                (__attribute__((address_space(3))) void*)(ldsb + slot * 16384 + j * 8192 + widoff),
                16, 0, 0);
        }
    };

    // ping-pong fragment sets (static indices only)
    bf16x8 af0[4], af1[4], bf0[4], bf1[4];

    f32x4 acc[8][4];
#pragma unroll
    for (int mi = 0; mi < 8; ++mi)
#pragma unroll
        for (int ni = 0; ni < 4; ++ni)
            acc[mi][ni] = (f32x4){0.f, 0.f, 0.f, 0.f};

#define RD_A(DST, SLOT, MH)                                                   \
    _Pragma("unroll")                                                         \
    for (int i = 0; i < 4; ++i) {                                             \
        const int row = wr * 128 + ((MH) * 4 + i) * 16 + lrow;                \
        DST[i] = *reinterpret_cast<const bf16x8*>(                            \
            ldsb + (SLOT) * 16384 + row * 64 + koff);                         \
    }
#define RD_B(DST, SLOT)                                                       \
    _Pragma("unroll")                                                         \
    for (int i = 0; i < 4; ++i) {                                             \
        const int row = wc * 64 + i * 16 + lrow;                              \
        DST[i] = *reinterpret_cast<const bf16x8*>(                            \
            ldsb + (SLOT) * 16384 + row * 64 + koff);                         \
    }
#define MFMA16(AF, BF, MH)                                                    \
    do { __builtin_amdgcn_s_setprio(1);                                       \
        _Pragma("unroll")                                                     \
        for (int mi = 0; mi < 4; ++mi)                                        \
            _Pragma("unroll")                                                 \
            for (int ni = 0; ni < 4; ++ni)                                    \
                acc[(MH) * 4 + mi][ni] = __builtin_amdgcn_mfma_f32_16x16x32_bf16( \
                    AF[mi], BF[ni], acc[(MH) * 4 + mi][ni], 0, 0, 0);         \
        __builtin_amdgcn_s_setprio(0); } while (0)
#define CLOSE                                                                 \
    do { __builtin_amdgcn_sched_barrier(0);                                   \
         __builtin_amdgcn_s_barrier();                                        \
         __builtin_amdgcn_sched_barrier(0); } while (0)
#define VM4 asm volatile("s_waitcnt vmcnt(4)" ::: "memory")
#define VM0 asm volatile("s_waitcnt vmcnt(0)" ::: "memory")

    // prologue: stage slots 0..5; retire s0..s3 before iter0's ph0-3 reads
    stage(0, Abase, 0, 0);
    stage(1, Bbase, 0, 0);
    stage(2, Abase, 0, 1);
    stage(3, Bbase, 0, 1);
    stage(4, Abase, 1, 0);
    stage(5, Bbase, 1, 0);
    VM4;
    CLOSE;

#pragma unroll 1
    for (int it = 0; it < NIT - 1; ++it) {
        const int tA = 2 * it + 1;       // <= 13
        const int tB = 2 * it + 2;       // <= 14
        const int tC = 2 * it + 3;       // <= 15

        // ph0
        RD_B(bf0, 1); RD_A(af0, 0, 0);
        stage(6, Abase, tA, 1);
        MFMA16(af0, bf0, 0);
        CLOSE;
        // ph1
        RD_A(af0, 0, 1);
        stage(7, Bbase, tA, 1);
        MFMA16(af0, bf0, 1);
        CLOSE;
        // ph2
        RD_B(bf1, 3); RD_A(af1, 2, 0);
        stage(0, Abase, tB, 0);
        MFMA16(af1, bf1, 0);
        CLOSE;
        // ph3
        RD_A(af1, 2, 1);
        stage(1, Bbase, tB, 0);
        MFMA16(af1, bf1, 1);
        VM4;                 // retires s4,s5,s6,s7 (8 oldest of 12)
        CLOSE;
        // ph4
        RD_B(bf0, 5); RD_A(af0, 4, 0);
        stage(2, Abase, tB, 1);
        MFMA16(af0, bf0, 0);
        CLOSE;
        // ph5
        RD_A(af0, 4, 1);
        stage(3, Bbase, tB, 1);
        MFMA16(af0, bf0, 1);
        CLOSE;
        // ph6
        RD_B(bf1, 7); RD_A(af1, 6, 0);
        stage(4, Abase, tC, 0);
        MFMA16(af1, bf1, 0);
        CLOSE;
        // ph7
        RD_A(af1, 6, 1);
        stage(5, Bbase, tC, 0);
        MFMA16(af1, bf1, 1);
        VM4;                 // retires next-iter s0,s1,s2,s3
        CLOSE;
    }

    // peeled last iteration (tA = 15; no tB/tC stages)
    {
        const int tA = 2 * (NIT - 1) + 1;    // 15
        RD_B(bf0, 1); RD_A(af0, 0, 0);
        stage(6, Abase, tA, 1);
        MFMA16(af0, bf0, 0);
        CLOSE;
        RD_A(af0, 0, 1);
        stage(7, Bbase, tA, 1);
        MFMA16(af0, bf0, 1);
        CLOSE;
        RD_B(bf1, 3); RD_A(af1, 2, 0);
        MFMA16(af1, bf1, 0);
        CLOSE;
        RD_A(af1, 2, 1);
        MFMA16(af1, bf1, 1);
        VM0;                 // retires s4,s5,s6,s7 (all 8 outstanding)
        CLOSE;
        RD_B(bf0, 5); RD_A(af0, 4, 0);
        MFMA16(af0, bf0, 0);
        CLOSE;
        RD_A(af0, 4, 1);
        MFMA16(af0, bf0, 1);
        CLOSE;
        RD_B(bf1, 7); RD_A(af1, 6, 0);
        MFMA16(af1, bf1, 0);
        CLOSE;
        RD_A(af1, 6, 1);
        MFMA16(af1, bf1, 1);
    }

#undef RD_A
#undef RD_B
#undef MFMA16
#undef CLOSE
#undef VM4
#undef VM0

    // ---- epilogue: bias + output fake-quant ----
    const float out_s = out_scale_p[0];
    const float out_inv = 1.0f / out_s;
    const float ozp = (float)out_zp_p[0];
    const int col = lane & 15;
    const int rgrp = lane >> 4;
#pragma unroll
    for (int ni = 0; ni < 4; ++ni) {
        const int n = n0 + wc * 64 + ni * 16 + col;
        const float bv = bias_f[n];
#pragma unroll
        for (int mi = 0; mi < 8; ++mi) {
#pragma unroll
            for (int j = 0; j < 4; ++j) {
                const int m = m0 + wr * 128 + mi * 16 + rgrp * 4 + j;
                float v = acc[mi][ni][j] + bv;
                float q = rintf(v * out_inv) + ozp;
                q = fminf(fmaxf(q, -128.0f), 127.0f);
                out[(size_t)m * N_DIM + n] = (q - ozp) * out_s;
            }
        }
    }
}

// ---------------- fallback (round-1): fused quant in A-staging, f32 x ----------------
__global__ __launch_bounds__(256) void gemm_fused_kernel(
    const float* __restrict__ x,
    const __hip_bfloat16* __restrict__ Wb,
    const float* __restrict__ bias_f,
    const float* __restrict__ in_scale_p, const int* __restrict__ in_zp_p,
    const float* __restrict__ out_scale_p, const int* __restrict__ out_zp_p,
    float* __restrict__ out)
{
    __shared__ __align__(16) __hip_bfloat16 As[2][FB_BM][FB_BK];
    __shared__ __align__(16) __hip_bfloat16 Bs[2][FB_BN][FB_BK];

    const int t = threadIdx.x;
    const int bid = blockIdx.x;
    const int nt = bid & 7;
    const int mt = bid >> 3;
    const int m0 = mt * FB_BM;
    const int n0 = nt * FB_BN;

    const int wid = t >> 6;
    const int lane = t & 63;
    const int wr = wid >> 1, wc = wid & 1;
    const int lrow = lane & 15;
    const int kslot = lane >> 4;

    const float in_s = in_scale_p[0];
    const float in_inv = 1.0f / in_s;
    const float izp = (float)in_zp_p[0];

    auto stageB = [&](int b, int kt) {
        const int k0 = kt * FB_BK;
#pragma unroll
        for (int j = 0; j < 2; ++j) {
            const int c = (wid * 2 + j) * 64 + lane;
            const int row = c >> 2;
            const int slot = c & 3;
            const __hip_bfloat16* src = Wb + (size_t)(n0 + row) * K_DIM + k0 + slot * 8;
            __builtin_amdgcn_global_load_lds(
                (const __attribute__((address_space(1))) void*)src,
                (__attribute__((address_space(3))) void*)((char*)&Bs[b][0][0] + (wid * 2 + j) * 1024),
                16, 0, 0);
        }
    };
    auto stageA = [&](int b, int kt) {
        const int k0 = kt * FB_BK;
#pragma unroll
        for (int i = 0; i < 4; ++i) {
            const int c = t + 256 * i;
            const int row = c >> 3;
            const int slot = c & 7;
            const float4 v = *reinterpret_cast<const float4*>(
                x + (size_t)(m0 + row) * K_DIM + k0 + slot * 4);
            float vv[4] = {v.x, v.y, v.z, v.w};
            union { ushort4 u; __hip_bfloat16 h[4]; } pk;
#pragma unroll
            for (int e = 0; e < 4; ++e) {
                float q = rintf(vv[e] * in_inv) + izp;
                q = fminf(fmaxf(q, -128.0f), 127.0f);
                pk.h[e] = __float2bfloat16((q - izp) * in_s);
            }
            *reinterpret_cast<ushort4*>(&As[b][row][slot * 4]) = pk.u;
        }
    };

    f32x4 acc[4][4];
#pragma unroll
    for (int mi = 0; mi < 4; ++mi)
#pragma unroll
        for (int ni = 0; ni < 4; ++ni)
            acc[mi][ni] = (f32x4){0.f, 0.f, 0.f, 0.f};

    stageB(0, 0);
    stageA(0, 0);
    __syncthreads();

    for (int kt = 0; kt < FB_NKT; ++kt) {
        const int buf = kt & 1;
        if (kt + 1 < FB_NKT) {
            stageB(buf ^ 1, kt + 1);
            stageA(buf ^ 1, kt + 1);
        }
        bf16x8 af[4], bfr[4];
#pragma unroll
        for (int mi = 0; mi < 4; ++mi)
            af[mi] = *reinterpret_cast<const bf16x8*>(&As[buf][wr * 64 + mi * 16 + lrow][kslot * 8]);
#pragma unroll
        for (int ni = 0; ni < 4; ++ni)
            bfr[ni] = *reinterpret_cast<const bf16x8*>(&Bs[buf][wc * 64 + ni * 16 + lrow][kslot * 8]);
#pragma unroll
        for (int mi = 0; mi < 4; ++mi)
#pragma unroll
            for (int ni = 0; ni < 4; ++ni)
                acc[mi][ni] = __builtin_amdgcn_mfma_f32_16x16x32_bf16(af[mi], bfr[ni], acc[mi][ni], 0, 0, 0);
        __syncthreads();
    }

    const float out_s = out_scale_p[0];
    const float out_inv = 1.0f / out_s;
    const float ozp = (float)out_zp_p[0];
    const int col = lane & 15;
    const int rgrp = lane >> 4;
#pragma unroll
    for (int ni = 0; ni < 4; ++ni) {
        const int n = n0 + wc * 64 + ni * 16 + col;
        const float bv = bias_f[n];
#pragma unroll
        for (int mi = 0; mi < 4; ++mi) {
#pragma unroll
            for (int j = 0; j < 4; ++j) {
                const int m = m0 + wr * 64 + mi * 16 + rgrp * 4 + j;
                float v = acc[mi][ni][j] + bv;
                float q = rintf(v * out_inv) + ozp;
                q = fminf(fmaxf(q, -128.0f), 127.0f);
                out[(size_t)m * N_DIM + n] = (q - ozp) * out_s;
            }
        }
    }
}

extern "C" void kernel_launch(void* const* d_in, const int* in_sizes, int n_in,
                              void* d_out, int out_size, void* d_ws, size_t ws_size,
                              hipStream_t stream) {
    const float* x          = (const float*)d_in[0];
    const int*   w_q        = (const int*)d_in[1];
    const float* w_scale    = (const float*)d_in[2];
    const int*   w_zp       = (const int*)d_in[3];
    const int*   bias_q     = (const int*)d_in[4];
    const float* bias_scale = (const float*)d_in[5];
    const float* in_scale   = (const float*)d_in[6];
    const int*   in_zp      = (const int*)d_in[7];
    const float* out_scale  = (const float*)d_in[8];
    const int*   out_zp     = (const int*)d_in[9];

    const size_t xq_bytes = (size_t)M_DIM * K_DIM * sizeof(__hip_bfloat16);  // 134 MB
    const size_t wb_bytes = (size_t)N_DIM * K_DIM * sizeof(__hip_bfloat16);  // 2 MB
    const size_t need = xq_bytes + wb_bytes + (size_t)N_DIM * sizeof(float);

    if (ws_size >= need) {
        __hip_bfloat16* Xq = (__hip_bfloat16*)d_ws;
        __hip_bfloat16* Wb = (__hip_bfloat16*)((char*)d_ws + xq_bytes);
        float* bias_f = (float*)((char*)d_ws + xq_bytes + wb_bytes);

        prep_kernel<<<N_DIM, 256, 0, stream>>>(w_q, w_scale, w_zp, bias_q, bias_scale, Wb, bias_f);
        prep_x_kernel<<<(M_DIM * (size_t)K_DIM) / (256 * 8), 256, 0, stream>>>(x, in_scale, in_zp, Xq);

        const int grid = (M_DIM / G_BM) * (N_DIM / G_BN);   // 256 * 4 = 1024
        gemm256_sb_kernel<<<grid, 512, 0, stream>>>(Xq, Wb, bias_f, out_scale, out_zp, (float*)d_out);
    } else {
        __hip_bfloat16* Wb = (__hip_bfloat16*)d_ws;
        float* bias_f = (float*)((char*)d_ws + wb_bytes);

        prep_kernel<<<N_DIM, 256, 0, stream>>>(w_q, w_scale, w_zp, bias_q, bias_scale, Wb, bias_f);
        const int grid = (M_DIM / FB_BM) * (N_DIM / FB_BN);
        gemm_fused_kernel<<<grid, 256, 0, stream>>>(x, Wb, bias_f, in_scale, in_zp,
                                                    out_scale, out_zp, (float*)d_out);
    }
}

// Round 8
// 229.808 us; speedup vs baseline: 1.2338x; 1.1308x over previous
//
#include <hip/hip_runtime.h>
#include <hip/hip_bf16.h>
#include <stdint.h>

// Problem constants (B=8, S=8192, K=1024, N=1024, G=128)
#define M_DIM 65536
#define K_DIM 1024
#define N_DIM 1024
#define NGRP  8

// 256x256 i8 GEMM geometry: 8 slots x (256 rows x 64 k-i8) = 16KB/slot
#define NIT 8                  // 8 iterations, K-128 (= 1 quant group) each

// fallback geometry (round-1 fused kernel)
#define FB_BM 128
#define FB_BN 128
#define FB_BK 32
#define FB_NKT (K_DIM / FB_BK)

typedef float f32x4 __attribute__((ext_vector_type(4)));
typedef int   ix4   __attribute__((ext_vector_type(4)));
typedef __bf16 bf16x8 __attribute__((ext_vector_type(8)));

// ---------------- prep: wd = w_q - w_zp (int8) [N][K], bias -> f32 ----------------
__global__ void prep_wd_kernel(const int* __restrict__ w_q,
                               const int* __restrict__ w_zp,
                               const int* __restrict__ bias_q,
                               const float* __restrict__ bias_scale,
                               int8_t* __restrict__ Wd,
                               float* __restrict__ bias_f) {
    const int n = blockIdx.x;       // 0..1023
    const int t = threadIdx.x;      // 0..255
    const int k0 = t * 4;
    const int g = k0 >> 7;
    const int zp = w_zp[n * NGRP + g];
    const int4 wq = *reinterpret_cast<const int4*>(w_q + (size_t)n * K_DIM + k0);
    union { int u; int8_t b[4]; } pk;
    pk.b[0] = (int8_t)(wq.x - zp);
    pk.b[1] = (int8_t)(wq.y - zp);
    pk.b[2] = (int8_t)(wq.z - zp);
    pk.b[3] = (int8_t)(wq.w - zp);
    *reinterpret_cast<int*>(Wd + (size_t)n * K_DIM + k0) = pk.u;
    if (t == 0) bias_f[n] = ((float)bias_q[n] - 128.0f) * bias_scale[n];
}

// ---------------- prep: fake-quant x -> int8 codes [M][K] ----------------
// x_hat = s * q with q = clip(round(x/s)+zp,-128,127) - zp  (zp=0 in data)
__global__ __launch_bounds__(256) void prep_x8_kernel(
    const float* __restrict__ x,
    const float* __restrict__ in_scale_p, const int* __restrict__ in_zp_p,
    int8_t* __restrict__ Xq)
{
    const float s = in_scale_p[0];
    const float inv = 1.0f / s;
    const float zp = (float)in_zp_p[0];
    const size_t i = ((size_t)blockIdx.x * 256 + threadIdx.x) * 16;
    float vv[16];
#pragma unroll
    for (int c = 0; c < 4; ++c) {
        const float4 v = *reinterpret_cast<const float4*>(x + i + c * 4);
        vv[c * 4 + 0] = v.x; vv[c * 4 + 1] = v.y;
        vv[c * 4 + 2] = v.z; vv[c * 4 + 3] = v.w;
    }
    union { int4 u; int8_t b[16]; } pk;
#pragma unroll
    for (int e = 0; e < 16; ++e) {
        float q = rintf(vv[e] * inv) + zp;       // RNE matches jnp.round
        q = fminf(fmaxf(q, -128.0f), 127.0f);
        pk.b[e] = (int8_t)(q - zp);
    }
    *reinterpret_cast<int4*>(Xq + i) = pk.u;
}

// ---------------- 256x256 int8 GEMM, 4 phases/iter (r7 skeleton) ----------------
// Slots (16KB = 256 rows x 64B): iter it uses base b=(it&1)*4:
//   b+0 = A k-tile 2it, b+1 = B 2it, b+2 = A 2it+1, b+3 = B 2it+1.
// Stages during it fill (b^4)+0..3 with tiles 2(it+1), 2(it+1)+1.
// Phase = { ds_reads | 1 stage | MFMA16 i8 (+CVT on ph1/ph3) | [vmcnt] | close }.
// Ledger (2 loads/stage): prologue 4 stages -> vmcnt(4) retires b0,b1.
//   ph0 end: 4 old + 2 staged = 6 -> vmcnt(2) retires b2,b3.
//   ph3 end: 8 outstanding -> vmcnt(4) retires next iter's A0,B0.
//   tail it=7: ph0 end vmcnt(0); no stages.
// WAR: each slot restaged >=2 close-barriers after its last ds_read.
// Group math: iter = one K-128 group; 2 MFMA (K-64) into i32, then
//   facc += ws[n,g] * (float)i32  (exact integer dot, f32 group combine).
__global__ __launch_bounds__(512, 2) void gemm256_i8_kernel(
    const int8_t* __restrict__ Xq,
    const int8_t* __restrict__ Wd,
    const float* __restrict__ w_scale,
    const float* __restrict__ bias_f,
    const float* __restrict__ in_scale_p,
    const float* __restrict__ out_scale_p, const int* __restrict__ out_zp_p,
    float* __restrict__ out)
{
    __shared__ __align__(16) int8_t LDS[8][16384];   // 128 KiB
    __shared__ float WS[NGRP * 256];                 // 8 KiB, [g][n_local]

    const int t = threadIdx.x;
    // bijective XCD swizzle: grid=1024, 8 XCDs, 128 blocks/XCD
    const int bid = (blockIdx.x & 7) * 128 + (blockIdx.x >> 3);
    const int nt = bid & 3;
    const int mt = bid >> 2;
    const int m0 = mt * 256;
    const int n0 = nt * 256;

    const int wid = t >> 6;
    const int lane = t & 63;
    const int wr = wid >> 2, wc = wid & 3;     // 2x4 waves, each owns 128x64 output
    const int lrow = lane & 15;
    const int kslot = lane >> 4;               // 16B k-chunk within 64B slot row
    const int koff = ((kslot ^ ((lrow >> 1) & 3)) << 4);   // swizzled (0-conflict r2-r7)
    const int widoff = wid * 1024;

    char* ldsb = (char*)&LDS[0][0];
    const int8_t* Abase = Xq + (size_t)m0 * K_DIM;
    const int8_t* Bbase = Wd + (size_t)n0 * K_DIM;

    // ---- preload w_scale panel into LDS [g][n_local] (before vmcnt ledger) ----
    {
        const int nl = t >> 1;                 // 0..255
        const int g4 = (t & 1) * 4;
        const float4 wv = *reinterpret_cast<const float4*>(
            w_scale + (size_t)(n0 + nl) * NGRP + g4);
        WS[(g4 + 0) * 256 + nl] = wv.x;
        WS[(g4 + 1) * 256 + nl] = wv.y;
        WS[(g4 + 2) * 256 + nl] = wv.z;
        WS[(g4 + 3) * 256 + nl] = wv.w;
    }
    asm volatile("s_waitcnt vmcnt(0) lgkmcnt(0)" ::: "memory");
    __builtin_amdgcn_s_barrier();
    __builtin_amdgcn_sched_barrier(0);

    // stage one slot (256 rows x 64B) via global_load_lds, pre-swizzled source
    auto stage = [&](int slot, const int8_t* panel, int kt64) {
        const int k0 = kt64 * 64;              // byte == elem offset (i8)
#pragma unroll
        for (int j = 0; j < 2; ++j) {
            const int c = j * 512 + t;                 // 16B chunk id 0..1023
            const int r = c >> 2;                      // row 0..255
            const int sl = (c & 3) ^ ((r >> 1) & 3);   // logical k-slot at phys slot
            const int8_t* src = panel + (size_t)r * K_DIM + k0 + sl * 16;
            __builtin_amdgcn_global_load_lds(
                (const __attribute__((address_space(1))) void*)src,
                (__attribute__((address_space(3))) void*)(ldsb + slot * 16384 + j * 8192 + widoff),
                16, 0, 0);
        }
    };

    ix4 af[4], bfr[4];      // transient fragment regs (re-read per phase)
    ix4 it0[4][4];          // i32 group partials, reused across mh halves
    f32x4 facc[8][4];
#pragma unroll
    for (int mi = 0; mi < 8; ++mi)
#pragma unroll
        for (int ni = 0; ni < 4; ++ni)
            facc[mi][ni] = (f32x4){0.f, 0.f, 0.f, 0.f};

#define RD_A(SLOT, MH)                                                        \
    _Pragma("unroll")                                                         \
    for (int i = 0; i < 4; ++i) {                                             \
        const int row = wr * 128 + ((MH) * 4 + i) * 16 + lrow;                \
        af[i] = *reinterpret_cast<const ix4*>(                                \
            ldsb + (SLOT) * 16384 + row * 64 + koff);                         \
    }
#define RD_B(SLOT)                                                            \
    _Pragma("unroll")                                                         \
    for (int i = 0; i < 4; ++i) {                                             \
        const int row = wc * 64 + i * 16 + lrow;                              \
        bfr[i] = *reinterpret_cast<const ix4*>(                               \
            ldsb + (SLOT) * 16384 + row * 64 + koff);                         \
    }
#define MFMA16_INIT                                                           \
    do { __builtin_amdgcn_s_setprio(1);                                       \
        _Pragma("unroll")                                                     \
        for (int mi = 0; mi < 4; ++mi)                                        \
            _Pragma("unroll")                                                 \
            for (int ni = 0; ni < 4; ++ni)                                    \
                it0[mi][ni] = __builtin_amdgcn_mfma_i32_16x16x64_i8(          \
                    af[mi], bfr[ni], (ix4){0, 0, 0, 0}, 0, 0, 0);             \
        __builtin_amdgcn_s_setprio(0); } while (0)
#define MFMA16_ACC                                                            \
    do { __builtin_amdgcn_s_setprio(1);                                       \
        _Pragma("unroll")                                                     \
        for (int mi = 0; mi < 4; ++mi)                                        \
            _Pragma("unroll")                                                 \
            for (int ni = 0; ni < 4; ++ni)                                    \
                it0[mi][ni] = __builtin_amdgcn_mfma_i32_16x16x64_i8(          \
                    af[mi], bfr[ni], it0[mi][ni], 0, 0, 0);                   \
        __builtin_amdgcn_s_setprio(0); } while (0)
#define CVT16(MH)                                                             \
    _Pragma("unroll")                                                         \
    for (int mi = 0; mi < 4; ++mi)                                            \
        _Pragma("unroll")                                                     \
        for (int ni = 0; ni < 4; ++ni)                                        \
            _Pragma("unroll")                                                 \
            for (int e = 0; e < 4; ++e)                                       \
                facc[(MH) * 4 + mi][ni][e] += wsv[ni] * (float)it0[mi][ni][e];
#define CLOSE                                                                 \
    do { __builtin_amdgcn_sched_barrier(0);                                   \
         __builtin_amdgcn_s_barrier();                                        \
         __builtin_amdgcn_sched_barrier(0); } while (0)
#define VM4 asm volatile("s_waitcnt vmcnt(4)" ::: "memory")
#define VM2 asm volatile("s_waitcnt vmcnt(2)" ::: "memory")
#define VM0 asm volatile("s_waitcnt vmcnt(0)" ::: "memory")

    // prologue: stage iter0's 4 slots; retire s0,s1 before ph0 reads
    stage(0, Abase, 0);
    stage(1, Bbase, 0);
    stage(2, Abase, 1);
    stage(3, Bbase, 1);
    VM4;
    CLOSE;

#pragma unroll 1
    for (int it = 0; it < NIT - 1; ++it) {
        const int b = (it & 1) * 4;
        const int nb = b ^ 4;
        const int tE = 2 * (it + 1);       // <= 14
        const int tO = tE + 1;             // <= 15
        const int nl = wc * 64 + lrow;

        float wsv[4];
#pragma unroll
        for (int ni = 0; ni < 4; ++ni) wsv[ni] = WS[it * 256 + nl + ni * 16];

        // ph0: k-tile even, mh0 (init)
        RD_B(b + 1); RD_A(b + 0, 0);
        stage(nb + 0, Abase, tE);
        MFMA16_INIT;
        VM2;
        CLOSE;
        // ph1: k-tile odd, mh0 (acc) + group combine mh0
        RD_B(b + 3); RD_A(b + 2, 0);
        stage(nb + 1, Bbase, tE);
        MFMA16_ACC;
        CVT16(0);
        CLOSE;
        // ph2: k-tile even, mh1 (init)
        RD_B(b + 1); RD_A(b + 0, 1);
        stage(nb + 2, Abase, tO);
        MFMA16_INIT;
        CLOSE;
        // ph3: k-tile odd, mh1 (acc) + group combine mh1
        RD_B(b + 3); RD_A(b + 2, 1);
        stage(nb + 3, Bbase, tO);
        MFMA16_ACC;
        CVT16(1);
        VM4;
        CLOSE;
    }

    // peeled tail iter (it=7, b=4): no stages; draining waits
    {
        const int it = NIT - 1;
        const int b = 4;
        const int nl = wc * 64 + lrow;
        float wsv[4];
#pragma unroll
        for (int ni = 0; ni < 4; ++ni) wsv[ni] = WS[it * 256 + nl + ni * 16];

        RD_B(b + 1); RD_A(b + 0, 0);
        MFMA16_INIT;
        VM0;                       // retires s6,s7 (last 4 outstanding)
        CLOSE;
        RD_B(b + 3); RD_A(b + 2, 0);
        MFMA16_ACC;
        CVT16(0);
        CLOSE;
        RD_B(b + 1); RD_A(b + 0, 1);
        MFMA16_INIT;
        CLOSE;
        RD_B(b + 3); RD_A(b + 2, 1);
        MFMA16_ACC;
        CVT16(1);
    }

#undef RD_A
#undef RD_B
#undef MFMA16_INIT
#undef MFMA16_ACC
#undef CVT16
#undef CLOSE
#undef VM4
#undef VM2
#undef VM0

    // ---- epilogue: v = in_s * facc + bias; output fake-quant ----
    const float in_s  = in_scale_p[0];
    const float out_s = out_scale_p[0];
    const float out_inv = 1.0f / out_s;
    const float ozp = (float)out_zp_p[0];
    const int col = lane & 15;
    const int rgrp = lane >> 4;
#pragma unroll
    for (int ni = 0; ni < 4; ++ni) {
        const int n = n0 + wc * 64 + ni * 16 + col;
        const float bv = bias_f[n];
#pragma unroll
        for (int mi = 0; mi < 8; ++mi) {
#pragma unroll
            for (int j = 0; j < 4; ++j) {
                const int m = m0 + wr * 128 + mi * 16 + rgrp * 4 + j;
                float v = in_s * facc[mi][ni][j] + bv;
                float q = rintf(v * out_inv) + ozp;
                q = fminf(fmaxf(q, -128.0f), 127.0f);
                out[(size_t)m * N_DIM + n] = (q - ozp) * out_s;
            }
        }
    }
}

// ---------------- fallback path (round-1 proven): bf16 fused ----------------
__global__ void prep_kernel(const int* __restrict__ w_q,
                            const float* __restrict__ w_scale,
                            const int* __restrict__ w_zp,
                            const int* __restrict__ bias_q,
                            const float* __restrict__ bias_scale,
                            __hip_bfloat16* __restrict__ Wb,
                            float* __restrict__ bias_f) {
    const int n = blockIdx.x;
    const int t = threadIdx.x;
    const int k0 = t * 4;
    const int g = k0 >> 7;
    const float s  = w_scale[n * NGRP + g];
    const float zp = (float)w_zp[n * NGRP + g];
    const int4 wq = *reinterpret_cast<const int4*>(w_q + (size_t)n * K_DIM + k0);
    union { ushort4 u; __hip_bfloat16 h[4]; } pk;
    pk.h[0] = __float2bfloat16(((float)wq.x - zp) * s);
    pk.h[1] = __float2bfloat16(((float)wq.y - zp) * s);
    pk.h[2] = __float2bfloat16(((float)wq.z - zp) * s);
    pk.h[3] = __float2bfloat16(((float)wq.w - zp) * s);
    *reinterpret_cast<ushort4*>(Wb + (size_t)n * K_DIM + k0) = pk.u;
    if (t == 0) bias_f[n] = ((float)bias_q[n] - 128.0f) * bias_scale[n];
}

__global__ __launch_bounds__(256) void gemm_fused_kernel(
    const float* __restrict__ x,
    const __hip_bfloat16* __restrict__ Wb,
    const float* __restrict__ bias_f,
    const float* __restrict__ in_scale_p, const int* __restrict__ in_zp_p,
    const float* __restrict__ out_scale_p, const int* __restrict__ out_zp_p,
    float* __restrict__ out)
{
    __shared__ __align__(16) __hip_bfloat16 As[2][FB_BM][FB_BK];
    __shared__ __align__(16) __hip_bfloat16 Bs[2][FB_BN][FB_BK];

    const int t = threadIdx.x;
    const int bid = blockIdx.x;
    const int nt = bid & 7;
    const int mt = bid >> 3;
    const int m0 = mt * FB_BM;
    const int n0 = nt * FB_BN;

    const int wid = t >> 6;
    const int lane = t & 63;
    const int wr = wid >> 1, wc = wid & 1;
    const int lrow = lane & 15;
    const int kslot = lane >> 4;

    const float in_s = in_scale_p[0];
    const float in_inv = 1.0f / in_s;
    const float izp = (float)in_zp_p[0];

    auto stageB = [&](int b, int kt) {
        const int k0 = kt * FB_BK;
#pragma unroll
        for (int j = 0; j < 2; ++j) {
            const int c = (wid * 2 + j) * 64 + lane;
            const int row = c >> 2;
            const int slot = c & 3;
            const __hip_bfloat16* src = Wb + (size_t)(n0 + row) * K_DIM + k0 + slot * 8;
            __builtin_amdgcn_global_load_lds(
                (const __attribute__((address_space(1))) void*)src,
                (__attribute__((address_space(3))) void*)((char*)&Bs[b][0][0] + (wid * 2 + j) * 1024),
                16, 0, 0);
        }
    };
    auto stageA = [&](int b, int kt) {
        const int k0 = kt * FB_BK;
#pragma unroll
        for (int i = 0; i < 4; ++i) {
            const int c = t + 256 * i;
            const int row = c >> 3;
            const int slot = c & 7;
            const float4 v = *reinterpret_cast<const float4*>(
                x + (size_t)(m0 + row) * K_DIM + k0 + slot * 4);
            float vv[4] = {v.x, v.y, v.z, v.w};
            union { ushort4 u; __hip_bfloat16 h[4]; } pk;
#pragma unroll
            for (int e = 0; e < 4; ++e) {
                float q = rintf(vv[e] * in_inv) + izp;
                q = fminf(fmaxf(q, -128.0f), 127.0f);
                pk.h[e] = __float2bfloat16((q - izp) * in_s);
            }
            *reinterpret_cast<ushort4*>(&As[b][row][slot * 4]) = pk.u;
        }
    };

    f32x4 acc[4][4];
#pragma unroll
    for (int mi = 0; mi < 4; ++mi)
#pragma unroll
        for (int ni = 0; ni < 4; ++ni)
            acc[mi][ni] = (f32x4){0.f, 0.f, 0.f, 0.f};

    stageB(0, 0);
    stageA(0, 0);
    __syncthreads();

    for (int kt = 0; kt < FB_NKT; ++kt) {
        const int buf = kt & 1;
        if (kt + 1 < FB_NKT) {
            stageB(buf ^ 1, kt + 1);
            stageA(buf ^ 1, kt + 1);
        }
        bf16x8 af[4], bfr[4];
#pragma unroll
        for (int mi = 0; mi < 4; ++mi)
            af[mi] = *reinterpret_cast<const bf16x8*>(&As[buf][wr * 64 + mi * 16 + lrow][kslot * 8]);
#pragma unroll
        for (int ni = 0; ni < 4; ++ni)
            bfr[ni] = *reinterpret_cast<const bf16x8*>(&Bs[buf][wc * 64 + ni * 16 + lrow][kslot * 8]);
#pragma unroll
        for (int mi = 0; mi < 4; ++mi)
#pragma unroll
            for (int ni = 0; ni < 4; ++ni)
                acc[mi][ni] = __builtin_amdgcn_mfma_f32_16x16x32_bf16(af[mi], bfr[ni], acc[mi][ni], 0, 0, 0);
        __syncthreads();
    }

    const float out_s = out_scale_p[0];
    const float out_inv = 1.0f / out_s;
    const float ozp = (float)out_zp_p[0];
    const int col = lane & 15;
    const int rgrp = lane >> 4;
#pragma unroll
    for (int ni = 0; ni < 4; ++ni) {
        const int n = n0 + wc * 64 + ni * 16 + col;
        const float bv = bias_f[n];
#pragma unroll
        for (int mi = 0; mi < 4; ++mi) {
#pragma unroll
            for (int j = 0; j < 4; ++j) {
                const int m = m0 + wr * 64 + mi * 16 + rgrp * 4 + j;
                float v = acc[mi][ni][j] + bv;
                float q = rintf(v * out_inv) + ozp;
                q = fminf(fmaxf(q, -128.0f), 127.0f);
                out[(size_t)m * N_DIM + n] = (q - ozp) * out_s;
            }
        }
    }
}

extern "C" void kernel_launch(void* const* d_in, const int* in_sizes, int n_in,
                              void* d_out, int out_size, void* d_ws, size_t ws_size,
                              hipStream_t stream) {
    const float* x          = (const float*)d_in[0];
    const int*   w_q        = (const int*)d_in[1];
    const float* w_scale    = (const float*)d_in[2];
    const int*   w_zp       = (const int*)d_in[3];
    const int*   bias_q     = (const int*)d_in[4];
    const float* bias_scale = (const float*)d_in[5];
    const float* in_scale   = (const float*)d_in[6];
    const int*   in_zp      = (const int*)d_in[7];
    const float* out_scale  = (const float*)d_in[8];
    const int*   out_zp     = (const int*)d_in[9];

    const size_t xq8_bytes = (size_t)M_DIM * K_DIM;          // 67.1 MB
    const size_t wd_bytes  = (size_t)N_DIM * K_DIM;          // 1 MB
    const size_t need = xq8_bytes + wd_bytes + N_DIM * sizeof(float);

    if (ws_size >= need) {
        int8_t* Xq8 = (int8_t*)d_ws;
        int8_t* Wd  = (int8_t*)((char*)d_ws + xq8_bytes);
        float* bias_f = (float*)((char*)d_ws + xq8_bytes + wd_bytes);

        prep_wd_kernel<<<N_DIM, 256, 0, stream>>>(w_q, w_zp, bias_q, bias_scale, Wd, bias_f);
        prep_x8_kernel<<<(int)(((size_t)M_DIM * K_DIM) / (256 * 16)), 256, 0, stream>>>(
            x, in_scale, in_zp, Xq8);

        const int grid = (M_DIM / 256) * (N_DIM / 256);   // 1024
        gemm256_i8_kernel<<<grid, 512, 0, stream>>>(Xq8, Wd, w_scale, bias_f,
                                                    in_scale, out_scale, out_zp,
                                                    (float*)d_out);
    } else {
        __hip_bfloat16* Wb = (__hip_bfloat16*)d_ws;
        float* bias_f = (float*)((char*)d_ws + (size_t)N_DIM * K_DIM * sizeof(__hip_bfloat16));

        prep_kernel<<<N_DIM, 256, 0, stream>>>(w_q, w_scale, w_zp, bias_q, bias_scale, Wb, bias_f);
        const int grid = (M_DIM / FB_BM) * (N_DIM / FB_BN);
        gemm_fused_kernel<<<grid, 256, 0, stream>>>(x, Wb, bias_f, in_scale, in_zp,
                                                    out_scale, out_zp, (float*)d_out);
    }
}

// Round 9
// 223.368 us; speedup vs baseline: 1.2694x; 1.0288x over previous
//
#include <hip/hip_runtime.h>
#include <hip/hip_bf16.h>
#include <stdint.h>

// Problem constants (B=8, S=8192, K=1024, N=1024, G=128)
#define M_DIM 65536
#define K_DIM 1024
#define N_DIM 1024
#define NGRP  8

// 128x128 i8 GEMM, BK=64, double-buffered, 3-4 blocks/CU (m97 mechanism)
#define T_BM 128
#define T_BN 128
#define T_BK 64
#define T_NKT (K_DIM / T_BK)    // 16

// fallback geometry (round-1 fused kernel)
#define FB_BM 128
#define FB_BN 128
#define FB_BK 32
#define FB_NKT (K_DIM / FB_BK)

typedef float f32x4 __attribute__((ext_vector_type(4)));
typedef int   ix4   __attribute__((ext_vector_type(4)));
typedef __bf16 bf16x8 __attribute__((ext_vector_type(8)));

// ---------------- prep: wd = w_q - w_zp (int8) [N][K], bias -> f32 ----------------
__global__ void prep_wd_kernel(const int* __restrict__ w_q,
                               const int* __restrict__ w_zp,
                               const int* __restrict__ bias_q,
                               const float* __restrict__ bias_scale,
                               int8_t* __restrict__ Wd,
                               float* __restrict__ bias_f) {
    const int n = blockIdx.x;       // 0..1023
    const int t = threadIdx.x;      // 0..255
    const int k0 = t * 4;
    const int g = k0 >> 7;
    const int zp = w_zp[n * NGRP + g];
    const int4 wq = *reinterpret_cast<const int4*>(w_q + (size_t)n * K_DIM + k0);
    union { int u; int8_t b[4]; } pk;
    pk.b[0] = (int8_t)(wq.x - zp);
    pk.b[1] = (int8_t)(wq.y - zp);
    pk.b[2] = (int8_t)(wq.z - zp);
    pk.b[3] = (int8_t)(wq.w - zp);
    *reinterpret_cast<int*>(Wd + (size_t)n * K_DIM + k0) = pk.u;
    if (t == 0) bias_f[n] = ((float)bias_q[n] - 128.0f) * bias_scale[n];
}

// ---------------- prep: fake-quant x -> int8 codes [M][K] ----------------
__global__ __launch_bounds__(256) void prep_x8_kernel(
    const float* __restrict__ x,
    const float* __restrict__ in_scale_p, const int* __restrict__ in_zp_p,
    int8_t* __restrict__ Xq)
{
    const float s = in_scale_p[0];
    const float inv = 1.0f / s;
    const float zp = (float)in_zp_p[0];
    const size_t i = ((size_t)blockIdx.x * 256 + threadIdx.x) * 16;
    float vv[16];
#pragma unroll
    for (int c = 0; c < 4; ++c) {
        const float4 v = *reinterpret_cast<const float4*>(x + i + c * 4);
        vv[c * 4 + 0] = v.x; vv[c * 4 + 1] = v.y;
        vv[c * 4 + 2] = v.z; vv[c * 4 + 3] = v.w;
    }
    union { int4 u; int8_t b[16]; } pk;
#pragma unroll
    for (int e = 0; e < 16; ++e) {
        float q = rintf(vv[e] * inv) + zp;       // RNE matches jnp.round
        q = fminf(fmaxf(q, -128.0f), 127.0f);
        pk.b[e] = (int8_t)(q - zp);
    }
    *reinterpret_cast<int4*>(Xq + i) = pk.u;
}

// ---------------- 128x128 i8 GEMM, m97-style multi-block overlap ----------------
// 256 thr = 4 waves (2x2), wave owns 64x64. BK=64 (one MFMA K per tile).
// LDS 36 KB -> 4 blocks by LDS; VGPR<=170 (launch_bounds min 3 waves/EU)
// -> ~3 blocks/CU resident: other blocks' waves fill this block's barrier
// drain (m97: 36% util with this exact mechanism, no counted vmcnt).
// Per K-64 tile: stage next buf (4 gload_lds/thread), read frags (8 b128),
// 16 MFMA i8 -> i32, exact per-tile group combine facc += ws_g * S_t,
// one __syncthreads (drains vmcnt+lgkm; WAR/RAW both covered).
__global__ __launch_bounds__(256, 3) void gemm128_i8_kernel(
    const int8_t* __restrict__ Xq,
    const int8_t* __restrict__ Wd,
    const float* __restrict__ w_scale,
    const float* __restrict__ bias_f,
    const float* __restrict__ in_scale_p,
    const float* __restrict__ out_scale_p, const int* __restrict__ out_zp_p,
    float* __restrict__ out)
{
    __shared__ __align__(16) int8_t Abuf[2][T_BM * T_BK];   // 2 x 8 KB
    __shared__ __align__(16) int8_t Bbuf[2][T_BN * T_BK];   // 2 x 8 KB
    __shared__ float WS[NGRP * T_BN];                        // 4 KB [g][n_local]

    const int t = threadIdx.x;
    // bijective XCD swizzle: grid=4096, 8 XCDs, 512 blocks/XCD;
    // consecutive local bids share the A panel (mt) across nt=0..7.
    const int bid = (blockIdx.x & 7) * 512 + (blockIdx.x >> 3);
    const int nt = bid & 7;
    const int mt = bid >> 3;
    const int m0 = mt * T_BM;
    const int n0 = nt * T_BN;

    const int wid = t >> 6;
    const int lane = t & 63;
    const int wr = wid >> 1, wc = wid & 1;     // 2x2 waves, each owns 64x64
    const int lrow = lane & 15;
    const int kslot = lane >> 4;               // 16B k-chunk within 64B row
    const int koff = ((kslot ^ ((lrow >> 1) & 3)) << 4);   // 0-conflict (r2-r8)
    const int widoff = wid * 1024;

    const int8_t* Abase = Xq + (size_t)m0 * K_DIM;
    const int8_t* Bbase = Wd + (size_t)n0 * K_DIM;

    // ---- preload w_scale panel [g][n_local] (drained by prologue barrier) ----
    {
        const int nl = t >> 1;                 // 0..127
        const int g4 = (t & 1) * 4;
        const float4 wv = *reinterpret_cast<const float4*>(
            w_scale + (size_t)(n0 + nl) * NGRP + g4);
        WS[(g4 + 0) * T_BN + nl] = wv.x;
        WS[(g4 + 1) * T_BN + nl] = wv.y;
        WS[(g4 + 2) * T_BN + nl] = wv.z;
        WS[(g4 + 3) * T_BN + nl] = wv.w;
    }

    // stage one 128x64B tile (512 chunks, 2/thread), pre-swizzled source
    auto stage = [&](int8_t* dst, const int8_t* panel, int kt) {
        const int k0 = kt * T_BK;
#pragma unroll
        for (int j = 0; j < 2; ++j) {
            const int c = j * 256 + t;                 // 16B chunk id 0..511
            const int r = c >> 2;                      // row 0..127
            const int sl = (c & 3) ^ ((r >> 1) & 3);   // logical k-slot at phys slot
            const int8_t* src = panel + (size_t)r * K_DIM + k0 + sl * 16;
            __builtin_amdgcn_global_load_lds(
                (const __attribute__((address_space(1))) void*)src,
                (__attribute__((address_space(3))) void*)(dst + j * 4096 + widoff),
                16, 0, 0);
        }
    };

    f32x4 facc[4][4];
#pragma unroll
    for (int mi = 0; mi < 4; ++mi)
#pragma unroll
        for (int ni = 0; ni < 4; ++ni)
            facc[mi][ni] = (f32x4){0.f, 0.f, 0.f, 0.f};

    // prologue: stage tile 0 into buf 0 (WS + DMA drained by syncthreads)
    stage(&Abuf[0][0], Abase, 0);
    stage(&Bbuf[0][0], Bbase, 0);
    __syncthreads();

    int buf = 0;
#pragma unroll 1
    for (int kt = 0; kt < T_NKT; ++kt) {
        if (kt + 1 < T_NKT) {
            stage(&Abuf[buf ^ 1][0], Abase, kt + 1);
            stage(&Bbuf[buf ^ 1][0], Bbase, kt + 1);
        }

        ix4 af[4], bfr[4];
#pragma unroll
        for (int i = 0; i < 4; ++i) {
            const int arow = wr * 64 + i * 16 + lrow;
            af[i] = *reinterpret_cast<const ix4*>(&Abuf[buf][arow * 64 + koff]);
        }
#pragma unroll
        for (int i = 0; i < 4; ++i) {
            const int brow = wc * 64 + i * 16 + lrow;
            bfr[i] = *reinterpret_cast<const ix4*>(&Bbuf[buf][brow * 64 + koff]);
        }

        const int g = kt >> 1;
        float wsv[4];
#pragma unroll
        for (int ni = 0; ni < 4; ++ni)
            wsv[ni] = WS[g * T_BN + wc * 64 + ni * 16 + lrow];

#pragma unroll
        for (int mi = 0; mi < 4; ++mi) {
            ix4 s0 = __builtin_amdgcn_mfma_i32_16x16x64_i8(af[mi], bfr[0], (ix4){0,0,0,0}, 0, 0, 0);
            ix4 s1 = __builtin_amdgcn_mfma_i32_16x16x64_i8(af[mi], bfr[1], (ix4){0,0,0,0}, 0, 0, 0);
            ix4 s2 = __builtin_amdgcn_mfma_i32_16x16x64_i8(af[mi], bfr[2], (ix4){0,0,0,0}, 0, 0, 0);
            ix4 s3 = __builtin_amdgcn_mfma_i32_16x16x64_i8(af[mi], bfr[3], (ix4){0,0,0,0}, 0, 0, 0);
#pragma unroll
            for (int e = 0; e < 4; ++e) {
                facc[mi][0][e] += wsv[0] * (float)s0[e];
                facc[mi][1][e] += wsv[1] * (float)s1[e];
                facc[mi][2][e] += wsv[2] * (float)s2[e];
                facc[mi][3][e] += wsv[3] * (float)s3[e];
            }
        }

        __syncthreads();
        buf ^= 1;
    }

    // ---- epilogue: v = in_s * facc + bias; output fake-quant ----
    const float in_s  = in_scale_p[0];
    const float out_s = out_scale_p[0];
    const float out_inv = 1.0f / out_s;
    const float ozp = (float)out_zp_p[0];
    const int col = lane & 15;
    const int rgrp = lane >> 4;
#pragma unroll
    for (int ni = 0; ni < 4; ++ni) {
        const int n = n0 + wc * 64 + ni * 16 + col;
        const float bv = bias_f[n];
#pragma unroll
        for (int mi = 0; mi < 4; ++mi) {
#pragma unroll
            for (int j = 0; j < 4; ++j) {
                const int m = m0 + wr * 64 + mi * 16 + rgrp * 4 + j;
                float v = in_s * facc[mi][ni][j] + bv;
                float q = rintf(v * out_inv) + ozp;
                q = fminf(fmaxf(q, -128.0f), 127.0f);
                out[(size_t)m * N_DIM + n] = (q - ozp) * out_s;
            }
        }
    }
}

// ---------------- fallback path (round-1 proven): bf16 fused ----------------
__global__ void prep_kernel(const int* __restrict__ w_q,
                            const float* __restrict__ w_scale,
                            const int* __restrict__ w_zp,
                            const int* __restrict__ bias_q,
                            const float* __restrict__ bias_scale,
                            __hip_bfloat16* __restrict__ Wb,
                            float* __restrict__ bias_f) {
    const int n = blockIdx.x;
    const int t = threadIdx.x;
    const int k0 = t * 4;
    const int g = k0 >> 7;
    const float s  = w_scale[n * NGRP + g];
    const float zp = (float)w_zp[n * NGRP + g];
    const int4 wq = *reinterpret_cast<const int4*>(w_q + (size_t)n * K_DIM + k0);
    union { ushort4 u; __hip_bfloat16 h[4]; } pk;
    pk.h[0] = __float2bfloat16(((float)wq.x - zp) * s);
    pk.h[1] = __float2bfloat16(((float)wq.y - zp) * s);
    pk.h[2] = __float2bfloat16(((float)wq.z - zp) * s);
    pk.h[3] = __float2bfloat16(((float)wq.w - zp) * s);
    *reinterpret_cast<ushort4*>(Wb + (size_t)n * K_DIM + k0) = pk.u;
    if (t == 0) bias_f[n] = ((float)bias_q[n] - 128.0f) * bias_scale[n];
}

__global__ __launch_bounds__(256) void gemm_fused_kernel(
    const float* __restrict__ x,
    const __hip_bfloat16* __restrict__ Wb,
    const float* __restrict__ bias_f,
    const float* __restrict__ in_scale_p, const int* __restrict__ in_zp_p,
    const float* __restrict__ out_scale_p, const int* __restrict__ out_zp_p,
    float* __restrict__ out)
{
    __shared__ __align__(16) __hip_bfloat16 As[2][FB_BM][FB_BK];
    __shared__ __align__(16) __hip_bfloat16 Bs[2][FB_BN][FB_BK];

    const int t = threadIdx.x;
    const int bid = blockIdx.x;
    const int nt = bid & 7;
    const int mt = bid >> 3;
    const int m0 = mt * FB_BM;
    const int n0 = nt * FB_BN;

    const int wid = t >> 6;
    const int lane = t & 63;
    const int wr = wid >> 1, wc = wid & 1;
    const int lrow = lane & 15;
    const int kslot = lane >> 4;

    const float in_s = in_scale_p[0];
    const float in_inv = 1.0f / in_s;
    const float izp = (float)in_zp_p[0];

    auto stageB = [&](int b, int kt) {
        const int k0 = kt * FB_BK;
#pragma unroll
        for (int j = 0; j < 2; ++j) {
            const int c = (wid * 2 + j) * 64 + lane;
            const int row = c >> 2;
            const int slot = c & 3;
            const __hip_bfloat16* src = Wb + (size_t)(n0 + row) * K_DIM + k0 + slot * 8;
            __builtin_amdgcn_global_load_lds(
                (const __attribute__((address_space(1))) void*)src,
                (__attribute__((address_space(3))) void*)((char*)&Bs[b][0][0] + (wid * 2 + j) * 1024),
                16, 0, 0);
        }
    };
    auto stageA = [&](int b, int kt) {
        const int k0 = kt * FB_BK;
#pragma unroll
        for (int i = 0; i < 4; ++i) {
            const int c = t + 256 * i;
            const int row = c >> 3;
            const int slot = c & 7;
            const float4 v = *reinterpret_cast<const float4*>(
                x + (size_t)(m0 + row) * K_DIM + k0 + slot * 4);
            float vv[4] = {v.x, v.y, v.z, v.w};
            union { ushort4 u; __hip_bfloat16 h[4]; } pk;
#pragma unroll
            for (int e = 0; e < 4; ++e) {
                float q = rintf(vv[e] * in_inv) + izp;
                q = fminf(fmaxf(q, -128.0f), 127.0f);
                pk.h[e] = __float2bfloat16((q - izp) * in_s);
            }
            *reinterpret_cast<ushort4*>(&As[b][row][slot * 4]) = pk.u;
        }
    };

    f32x4 acc[4][4];
#pragma unroll
    for (int mi = 0; mi < 4; ++mi)
#pragma unroll
        for (int ni = 0; ni < 4; ++ni)
            acc[mi][ni] = (f32x4){0.f, 0.f, 0.f, 0.f};

    stageB(0, 0);
    stageA(0, 0);
    __syncthreads();

    for (int kt = 0; kt < FB_NKT; ++kt) {
        const int buf = kt & 1;
        if (kt + 1 < FB_NKT) {
            stageB(buf ^ 1, kt + 1);
            stageA(buf ^ 1, kt + 1);
        }
        bf16x8 af[4], bfr[4];
#pragma unroll
        for (int mi = 0; mi < 4; ++mi)
            af[mi] = *reinterpret_cast<const bf16x8*>(&As[buf][wr * 64 + mi * 16 + lrow][kslot * 8]);
#pragma unroll
        for (int ni = 0; ni < 4; ++ni)
            bfr[ni] = *reinterpret_cast<const bf16x8*>(&Bs[buf][wc * 64 + ni * 16 + lrow][kslot * 8]);
#pragma unroll
        for (int mi = 0; mi < 4; ++mi)
#pragma unroll
            for (int ni = 0; ni < 4; ++ni)
                acc[mi][ni] = __builtin_amdgcn_mfma_f32_16x16x32_bf16(af[mi], bfr[ni], acc[mi][ni], 0, 0, 0);
        __syncthreads();
    }

    const float out_s = out_scale_p[0];
    const float out_inv = 1.0f / out_s;
    const float ozp = (float)out_zp_p[0];
    const int col = lane & 15;
    const int rgrp = lane >> 4;
#pragma unroll
    for (int ni = 0; ni < 4; ++ni) {
        const int n = n0 + wc * 64 + ni * 16 + col;
        const float bv = bias_f[n];
#pragma unroll
        for (int mi = 0; mi < 4; ++mi) {
#pragma unroll
            for (int j = 0; j < 4; ++j) {
                const int m = m0 + wr * 64 + mi * 16 + rgrp * 4 + j;
                float v = acc[mi][ni][j] + bv;
                float q = rintf(v * out_inv) + ozp;
                q = fminf(fmaxf(q, -128.0f), 127.0f);
                out[(size_t)m * N_DIM + n] = (q - ozp) * out_s;
            }
        }
    }
}

extern "C" void kernel_launch(void* const* d_in, const int* in_sizes, int n_in,
                              void* d_out, int out_size, void* d_ws, size_t ws_size,
                              hipStream_t stream) {
    const float* x          = (const float*)d_in[0];
    const int*   w_q        = (const int*)d_in[1];
    const float* w_scale    = (const float*)d_in[2];
    const int*   w_zp       = (const int*)d_in[3];
    const int*   bias_q     = (const int*)d_in[4];
    const float* bias_scale = (const float*)d_in[5];
    const float* in_scale   = (const float*)d_in[6];
    const int*   in_zp      = (const int*)d_in[7];
    const float* out_scale  = (const float*)d_in[8];
    const int*   out_zp     = (const int*)d_in[9];

    const size_t xq8_bytes = (size_t)M_DIM * K_DIM;          // 67.1 MB
    const size_t wd_bytes  = (size_t)N_DIM * K_DIM;          // 1 MB
    const size_t need = xq8_bytes + wd_bytes + N_DIM * sizeof(float);

    if (ws_size >= need) {
        int8_t* Xq8 = (int8_t*)d_ws;
        int8_t* Wd  = (int8_t*)((char*)d_ws + xq8_bytes);
        float* bias_f = (float*)((char*)d_ws + xq8_bytes + wd_bytes);

        prep_wd_kernel<<<N_DIM, 256, 0, stream>>>(w_q, w_zp, bias_q, bias_scale, Wd, bias_f);
        prep_x8_kernel<<<(int)(((size_t)M_DIM * K_DIM) / (256 * 16)), 256, 0, stream>>>(
            x, in_scale, in_zp, Xq8);

        const int grid = (M_DIM / T_BM) * (N_DIM / T_BN);   // 512 * 8 = 4096
        gemm128_i8_kernel<<<grid, 256, 0, stream>>>(Xq8, Wd, w_scale, bias_f,
                                                    in_scale, out_scale, out_zp,
                                                    (float*)d_out);
    } else {
        __hip_bfloat16* Wb = (__hip_bfloat16*)d_ws;
        float* bias_f = (float*)((char*)d_ws + (size_t)N_DIM * K_DIM * sizeof(__hip_bfloat16));

        prep_kernel<<<N_DIM, 256, 0, stream>>>(w_q, w_scale, w_zp, bias_q, bias_scale, Wb, bias_f);
        const int grid = (M_DIM / FB_BM) * (N_DIM / FB_BN);
        gemm_fused_kernel<<<grid, 256, 0, stream>>>(x, Wb, bias_f, in_scale, in_zp,
                                                    out_scale, out_zp, (float*)d_out);
    }
}